// Round 15
// baseline (145.163 us; speedup 1.0000x reference)
//
#include <hip/hip_runtime.h>
#include <hip/hip_bf16.h>

#define HWs   16384
#define Wimg  128
#define Himg  128
#define PW    130
#define PHW   16900      // 130*130 padded pixels
#define Cin   256
#define Oout  256
#define CKd   2304
#define Bb    2

typedef short   bf16x8 __attribute__((ext_vector_type(8)));
typedef float   f32x4  __attribute__((ext_vector_type(4)));
typedef float   f32x2  __attribute__((ext_vector_type(2)));

__device__ __forceinline__ ushort f2bf(float f){
  union { float f; unsigned int i; } v; v.f = f;
  return (ushort)((v.i + 0x8000u) >> 16);
}
__device__ __forceinline__ unsigned cvt_pk_bf16(float lo, float hi){
  unsigned r;
  asm("v_cvt_pk_bf16_f32 %0, %1, %2" : "=v"(r) : "v"(lo), "v"(hi));
  return r;
}
__device__ __forceinline__ void gload_lds16(const ushort* g, void* l){
  __builtin_amdgcn_global_load_lds(
      (const __attribute__((address_space(1))) unsigned int*)g,
      (__attribute__((address_space(3))) unsigned int*)l, 16, 0, 0);
}

// ---------------- x [B,C,H,W] fp32 -> xtp [B][130*130][C] bf16 (interior) ----------------
__global__ __launch_bounds__(256) void k_transpose(const float* __restrict__ x,
                                                   ushort* __restrict__ xtp){
  int bx = blockIdx.x;                 // 2048
  int b  = bx >> 10;
  int r  = bx & 1023;
  int ct = r >> 8;
  int pt = r & 255;
  int c0 = ct * 64, p0 = pt * 64;
  __shared__ float tile[64][65];
  const float* xb = x + (size_t)b * Cin * HWs;
  #pragma unroll
  for (int pass = 0; pass < 16; ++pass){
    int idx = pass * 256 + threadIdx.x;
    int cl = idx >> 6, pl = idx & 63;
    tile[cl][pl] = xb[(size_t)(c0 + cl) * HWs + p0 + pl];
  }
  __syncthreads();
  ushort* xo = xtp + (size_t)b * PHW * Cin;
  #pragma unroll
  for (int pass = 0; pass < 16; ++pass){
    int idx = pass * 256 + threadIdx.x;
    int pl = idx >> 6, cl = idx & 63;
    int hw = p0 + pl; int y = hw >> 7, xc = hw & 127;
    xo[(size_t)((y + 1) * PW + xc + 1) * Cin + c0 + cl] = f2bf(tile[cl][pl]);
  }
}

// ---------------- zero the padded border ----------------
__global__ __launch_bounds__(64) void k_border(ushort* __restrict__ xtp){
  int e = blockIdx.x;                  // 2 * 516
  int b = e / 516, p = e % 516;
  int y, xc;
  if (p < 130)      { y = 0;       xc = p; }
  else if (p < 260) { y = 129;     xc = p - 130; }
  else if (p < 388) { y = p - 259; xc = 0; }
  else              { y = p - 387; xc = 129; }
  uint2* dst = (uint2*)(xtp + ((size_t)b * PHW + y * PW + xc) * Cin) + threadIdx.x;
  *dst = make_uint2(0u, 0u);
}

// ---------------- weights -> k-major bf16: w2 [256][2304], w2of [32][2304] ----------------
__global__ __launch_bounds__(256) void k_wprep(const float* __restrict__ w,
                                               const float* __restrict__ wof,
                                               ushort* __restrict__ w2,
                                               ushort* __restrict__ w2of){
  int idx = blockIdx.x * 256 + threadIdx.x;    // 2592*256
  if (idx < Oout * CKd){
    int o = idx / CKd, r = idx % CKd;
    int k = r >> 8, c = r & 255;
    w2[idx] = f2bf(w[(size_t)(o * Cin + c) * 9 + k]);
  } else {
    int j = idx - Oout * CKd;
    int o = j / CKd, r = j % CKd;
    int k = r >> 8, c = r & 255;
    float v = (o < 18) ? wof[(size_t)(o * Cin + c) * 9 + k] : 0.f;
    w2of[j] = f2bf(v);
  }
}

// ---------------- offset conv (M=32 bf16 MFMA, BN=64, dbuf) + fused prep ----------------
// pw stores SEPARABLE masked weights: (wy0m, wy1m, wx0m, wx1m)
__global__ __launch_bounds__(512, 4) void k_offconv(const ushort* __restrict__ xtp,
                                                    const ushort* __restrict__ w2of,
                                                    const float* __restrict__ b_off,
                                                    int4* __restrict__ pidx,
                                                    float4* __restrict__ pw){
  int bx = blockIdx.x;                          // 512
  int blkm = ((bx & 7) << 6) | (bx >> 3);       // XCD-chunked swizzle
  int b = blkm >> 8, tile = blkm & 255;
  int hw0 = tile * 64;
  int iy = tile >> 1, jx0 = (tile & 1) * 64;
  __shared__ __align__(16) ushort aw[2][2048];
  __shared__ __align__(16) ushort bv_s[2][4096];
  __shared__ float offs_lds[18][64];
  int t = threadIdx.x, lane = t & 63, wid = t >> 6;
  int mi = wid >> 2, ni = wid & 3;
  f32x4 acc = (f32x4){0,0,0,0};
  const ushort* xb = xtp + (size_t)b * PHW * Cin;

#define OSTAGE(S, P) \
  if ((S) < 36){ int kks = (S) * 64, kt = (S) >> 2, c0s = ((S) * 64) & 255; \
    int dy = kt / 3 - 1, dxx = kt % 3 - 1; \
    if (wid < 4){ int L = t * 16; int oo = L >> 7; int inb = (L & 127) ^ ((oo & 7) << 4); \
      gload_lds16(w2of + (size_t)oo * CKd + kks + (inb >> 1), (char*)aw[P] + L); } \
    { int L = t * 16; int hw_l = L >> 7; int inb = (L & 127) ^ ((hw_l & 7) << 4); \
      int row = (iy + dy + 1) * PW + (jx0 + hw_l + dxx + 1); \
      gload_lds16(xb + (size_t)row * Cin + c0s + (inb >> 1), (char*)bv_s[P] + L); } }

  OSTAGE(0, 0);
  __syncthreads();
  #pragma unroll 1
  for (int step = 0; step < 36; ++step){
    int P = step & 1;
    OSTAGE(step + 1, P ^ 1);
    #pragma unroll
    for (int kk2 = 0; kk2 < 2; ++kk2){
      int coff = kk2 * 64 + ((lane >> 4) << 4);
      bf16x8 a0, bb;
      { int r = mi * 16 + (lane & 15); int byte = r * 128 + coff; byte ^= ((r & 7) << 4); a0 = *(const bf16x8*)((char*)aw[P] + byte); }
      { int r = ni * 16 + (lane & 15); int byte = r * 128 + coff; byte ^= ((r & 7) << 4); bb = *(const bf16x8*)((char*)bv_s[P] + byte); }
      acc = __builtin_amdgcn_mfma_f32_16x16x32_bf16(a0, bb, acc, 0, 0, 0);
    }
    __syncthreads();
  }
#undef OSTAGE
  {
    int hw_l = ni * 16 + (lane & 15);
    #pragma unroll
    for (int r = 0; r < 4; ++r){
      int o = mi * 16 + ((lane >> 4) << 2) + r;
      if (o < 18) offs_lds[o][hw_l] = acc[r] + b_off[o];
    }
  }
  __syncthreads();
  for (int idx = t; idx < 9 * 64; idx += 512){
    int k = idx >> 6, jl = idx & 63;
    int hw = hw0 + jl;
    int i = hw >> 7, jcol = hw & 127;
    float offy = offs_lds[2 * k][jl];
    float offx = offs_lds[2 * k + 1][jl];
    float py = (float)i    + (float)(k / 3 - 1) + offy;
    float px = (float)jcol + (float)(k % 3 - 1) + offx;
    float y0f = floorf(py), x0f = floorf(px);
    float ly = py - y0f, lx = px - x0f;
    int y0 = (int)y0f, x0 = (int)x0f;
    int y1 = y0 + 1, x1 = x0 + 1;
    bool vy0 = (y0 >= 0 && y0 < 128), vy1 = (y1 >= 0 && y1 < 128);
    bool vx0 = (x0 >= 0 && x0 < 128), vx1 = (x1 >= 0 && x1 < 128);
    int iy0 = min(max(y0, 0), 127), iy1 = min(max(y1, 0), 127);
    int ix0 = min(max(x0, 0), 127), ix1 = min(max(x1, 0), 127);
    size_t e = ((size_t)b * 9 + k) * HWs + hw;
    pidx[e] = make_int4(((iy0 + 1) * PW + ix0 + 1) * Cin, ((iy0 + 1) * PW + ix1 + 1) * Cin,
                        ((iy1 + 1) * PW + ix0 + 1) * Cin, ((iy1 + 1) * PW + ix1 + 1) * Cin);
    pw[e]   = make_float4(vy0 ? (1.f - ly) : 0.f, vy1 ? ly : 0.f,
                          vx0 ? (1.f - lx) : 0.f, vx1 ? lx : 0.f);
  }
}

// ---------------- separable bilinear combine: 4 bf16 corner dwords -> packed bf16x2 ----------------
__device__ __forceinline__ f32x2 up2(unsigned d){
  f32x2 r; r.x = __uint_as_float(d << 16); r.y = __uint_as_float(d & 0xFFFF0000u); return r;
}
__device__ __forceinline__ unsigned combine_pair(unsigned d00, unsigned d01, unsigned d10, unsigned d11,
                                                 float4 wt){   // wt = (wy0m, wy1m, wx0m, wx1m)
  f32x2 t0 = wt.z * up2(d00) + wt.w * up2(d01);
  f32x2 t1 = wt.z * up2(d10) + wt.w * up2(d11);
  f32x2 e  = wt.x * t0 + wt.y * t1;
  return cvt_pk_bf16(e.x, e.y);
}

// ---------------- fused gather + main GEMM: producer/consumer wave specialization ----------------
// 16 waves: wid 0..7 = consumers (ds_read + MFMA only), wid 8..15 = producers
// (corner gather + combine + A/B staging). BM=256, BN=64; grid 512.
// LDS: A dbuf 2x32KB + B dbuf 2x8KB = 80KB.
template<int BF16OUT>
__global__ __launch_bounds__(1024, 4) void k_main(const ushort* __restrict__ xtp,
                                                  const ushort* __restrict__ w2,
                                                  const int4* __restrict__ pidx,
                                                  const float4* __restrict__ pw,
                                                  void* __restrict__ outp,
                                                  float* __restrict__ partials){
  int bx = blockIdx.x;                          // 512
  int blkm = ((bx & 7) << 6) | (bx >> 3);       // XCD-chunked swizzle (512%8==0)
  int b = blkm >> 8, tile = blkm & 255;
  int hw0 = tile * 64;
  __shared__ __align__(16) ushort smem[40960];  // 80KB
  ushort* Ab0 = smem;                           // 32KB: 256 rows x 64ch swizzled
  ushort* Ab1 = smem + 16384;
  ushort* Bb0 = smem + 32768;                   // 8KB: 64px x 64ch swizzled
  ushort* Bb1 = smem + 36864;
  int t = threadIdx.x, lane = t & 63, wid = t >> 6;   // 16 waves
  // consumer coords (wid 0..7): 4x2 wave grid, 64o x 32hw each
  int wm = wid >> 1, wn = wid & 1;
  // producer coords (wid 8..15)
  int pt = t - 512;                              // 0..511
  int pwid = wid - 8;                            // 0..7
  int cg = pt & 7, hl = pt >> 3;                 // c-group 0..7, pixel 0..63
  f32x4 acc[4][2];
  #pragma unroll
  for (int mi = 0; mi < 4; ++mi)
    #pragma unroll
    for (int ni = 0; ni < 2; ++ni) acc[mi][ni] = (f32x4){0,0,0,0};
  const ushort* xb  = xtp  + (size_t)b * PHW * Cin;
  const int4*   pib = pidx + (size_t)b * 9 * HWs + hw0;
  const float4* pwb = pw   + (size_t)b * 9 * HWs + hw0;

  int4   ids[2];               // [parity], pre-scaled by Cin (producer only)
  float4 wts[2];
  uint4  g[2][4];              // [parity][corner] (producer only)

#define IDSLOAD(P, S) \
  if ((S) < 36){ int kq = (S) >> 2; ids[P] = pib[(size_t)kq * HWs + hl]; }

#define CORNERS(P, S) \
  if ((S) < 36){ int cb = (((S) * 64) & 255) + cg * 8; int kq = (S) >> 2; \
    wts[P] = pwb[(size_t)kq * HWs + hl]; \
    g[P][0] = *(const uint4*)(xb + ids[P].x + cb); \
    g[P][1] = *(const uint4*)(xb + ids[P].y + cb); \
    g[P][2] = *(const uint4*)(xb + ids[P].z + cb); \
    g[P][3] = *(const uint4*)(xb + ids[P].w + cb); }

#define STAGEA(S, ABP) \
  if ((S) < 36){ int kks = (S) * 64; \
    _Pragma("unroll") for (int h2 = 0; h2 < 4; ++h2){ \
      int L = (pwid * 4 + h2) * 1024 + lane * 16; \
      int oo = L >> 7; int inb = (L & 127) ^ ((oo & 7) << 4); \
      gload_lds16(w2 + (size_t)oo * CKd + kks + (inb >> 1), (char*)(ABP) + L); } }

#define COMBINE(P, S, BBP) \
  if ((S) < 36){ \
    float4 wtv = wts[P]; \
    uint4 ov; \
    ov.x = combine_pair(g[P][0].x, g[P][1].x, g[P][2].x, g[P][3].x, wtv); \
    ov.y = combine_pair(g[P][0].y, g[P][1].y, g[P][2].y, g[P][3].y, wtv); \
    ov.z = combine_pair(g[P][0].z, g[P][1].z, g[P][2].z, g[P][3].z, wtv); \
    ov.w = combine_pair(g[P][0].w, g[P][1].w, g[P][2].w, g[P][3].w, wtv); \
    int byte = hl * 128 + cg * 16; byte ^= ((hl & 7) << 4); \
    *(uint4*)((char*)(BBP) + byte) = ov; }

#define MFMA_PHASE(ABP, BBP) \
  { _Pragma("unroll") for (int kk2 = 0; kk2 < 2; ++kk2){ \
      int coff = kk2 * 64 + ((lane >> 4) << 4); \
      bf16x8 a[4], bv[2]; \
      _Pragma("unroll") for (int mi = 0; mi < 4; ++mi){ \
        int r = wm * 64 + mi * 16 + (lane & 15); \
        int byte = r * 128 + coff; byte ^= ((r & 7) << 4); \
        a[mi] = *(const bf16x8*)((const char*)(ABP) + byte); } \
      _Pragma("unroll") for (int ni = 0; ni < 2; ++ni){ \
        int r = wn * 32 + ni * 16 + (lane & 15); \
        int byte = r * 128 + coff; byte ^= ((r & 7) << 4); \
        bv[ni] = *(const bf16x8*)((const char*)(BBP) + byte); } \
      _Pragma("unroll") for (int mi = 0; mi < 4; ++mi) \
        _Pragma("unroll") for (int ni = 0; ni < 2; ++ni) \
          acc[mi][ni] = __builtin_amdgcn_mfma_f32_16x16x32_bf16(a[mi], bv[ni], acc[mi][ni], 0, 0, 0); } }

  // ---- prologue (producers stage tile 0, prefetch corners 0 & 1) ----
  if (wid >= 8){
    IDSLOAD(0, 0);
    IDSLOAD(1, 1);
    CORNERS(0, 0);
    IDSLOAD(0, 2);
    CORNERS(1, 1);
    IDSLOAD(1, 3);
    STAGEA(0, Ab0);
    COMBINE(0, 0, Bb0);
  }
  __syncthreads();

  // ---- main loop: consumers eat tile T while producers build tile T+1 ----
  #pragma unroll 1
  for (int tt = 0; tt < 36; tt += 2){
    // even phase T=tt
    if (wid >= 8){
      CORNERS(0, tt + 2);
      STAGEA(tt + 1, Ab1);
      IDSLOAD(0, tt + 4);
      COMBINE(1, tt + 1, Bb1);
    } else {
      MFMA_PHASE(Ab0, Bb0);
    }
    __syncthreads();
    // odd phase T=tt+1
    if (wid >= 8){
      CORNERS(1, tt + 3);
      STAGEA(tt + 2, Ab0);
      IDSLOAD(1, tt + 5);
      COMBINE(0, tt + 2, Bb0);
    } else {
      MFMA_PHASE(Ab1, Bb1);
    }
    __syncthreads();
  }
#undef IDSLOAD
#undef CORNERS
#undef STAGEA
#undef COMBINE
#undef MFMA_PHASE

  // ---- epilogue: consumers write C + BN partials ----
  if (wid < 8){
    #pragma unroll
    for (int mi = 0; mi < 4; ++mi){
      int obase = wm * 64 + mi * 16 + ((lane >> 4) << 2);
      #pragma unroll
      for (int ni = 0; ni < 2; ++ni){
        int hw = hw0 + wn * 32 + ni * 16 + (lane & 15);
        if (BF16OUT){
          ushort* ob = (ushort*)outp + ((size_t)b * Oout + obase) * HWs + hw;
          #pragma unroll
          for (int r = 0; r < 4; ++r) ob[(size_t)r * HWs] = f2bf(acc[mi][ni][r]);
        } else {
          float* op = (float*)outp + ((size_t)b * Oout + obase) * HWs + hw;
          #pragma unroll
          for (int r = 0; r < 4; ++r) op[(size_t)r * HWs] = acc[mi][ni][r];
        }
      }
    }
    #pragma unroll
    for (int mi = 0; mi < 4; ++mi){
      #pragma unroll
      for (int r = 0; r < 4; ++r){
        float s = 0.f, s2 = 0.f;
        #pragma unroll
        for (int ni = 0; ni < 2; ++ni){ float v = acc[mi][ni][r]; s += v; s2 += v * v; }
        #pragma unroll
        for (int off2 = 1; off2 < 16; off2 <<= 1){
          s  += __shfl_xor(s, off2);
          s2 += __shfl_xor(s2, off2);
        }
        if ((lane & 15) == 0){
          int o = wm * 64 + mi * 16 + ((lane >> 4) << 2) + r;
          int row = blkm * 2 + wn;               // 0..1023
          partials[(size_t)row * 256 + o] = s;
          partials[(size_t)1024 * 256 + (size_t)row * 256 + o] = s2;
        }
      }
    }
  }
}

// ---------------- BN stats from partials ----------------
__global__ __launch_bounds__(256) void k_bnstats(const float* __restrict__ partials,
                                                 float* __restrict__ stats){
  int o = blockIdx.x, t = threadIdx.x;
  float s = 0.f, s2 = 0.f;
  for (int i = t; i < 1024; i += 256){
    s  += partials[(size_t)i * 256 + o];
    s2 += partials[(size_t)1024 * 256 + (size_t)i * 256 + o];
  }
  #pragma unroll
  for (int off = 32; off > 0; off >>= 1){
    s  += __shfl_down(s, off);
    s2 += __shfl_down(s2, off);
  }
  __shared__ float rs[4], rs2[4];
  int lane = t & 63, w = t >> 6;
  if (lane == 0){ rs[w] = s; rs2[w] = s2; }
  __syncthreads();
  if (t == 0){
    float S = 0.f, S2 = 0.f;
    for (int i = 0; i < 4; ++i){ S += rs[i]; S2 += rs2[i]; }
    float mean = S / 32768.f;
    float var  = S2 / 32768.f - mean * mean;
    stats[o] = mean;
    stats[256 + o] = rsqrtf(var + 1e-5f);
  }
}

// ---------------- normalize + ReLU: fp32 in-place (fallback) ----------------
__global__ __launch_bounds__(256) void k_bnapply(float* __restrict__ out,
                                                 const float* __restrict__ stats,
                                                 const float* __restrict__ gamma,
                                                 const float* __restrict__ beta){
  size_t e = ((size_t)blockIdx.x * 256 + threadIdx.x) * 4;
  int o = (int)((e >> 14) & 255);
  float mean = stats[o], rstd = stats[256 + o];
  float sc = rstd * gamma[o];
  float sh = beta[o] - mean * sc;
  float4 v = *(float4*)(out + e);
  v.x = fmaxf(v.x * sc + sh, 0.f);
  v.y = fmaxf(v.y * sc + sh, 0.f);
  v.z = fmaxf(v.z * sc + sh, 0.f);
  v.w = fmaxf(v.w * sc + sh, 0.f);
  *(float4*)(out + e) = v;
}

// ---------------- normalize + ReLU: bf16 -> fp32 ----------------
__global__ __launch_bounds__(256) void k_bnapply_b(const ushort* __restrict__ outb,
                                                   float* __restrict__ out,
                                                   const float* __restrict__ stats,
                                                   const float* __restrict__ gamma,
                                                   const float* __restrict__ beta){
  size_t e = ((size_t)blockIdx.x * 256 + threadIdx.x) * 8;   // 4096 blocks
  int o = (int)((e >> 14) & 255);
  float mean = stats[o], rstd = stats[256 + o];
  float sc = rstd * gamma[o];
  float sh = beta[o] - mean * sc;
  uint4 v = *(const uint4*)(outb + e);
  float4 r0, r1;
  r0.x = fmaxf(__uint_as_float(v.x << 16)          * sc + sh, 0.f);
  r0.y = fmaxf(__uint_as_float(v.x & 0xFFFF0000u)  * sc + sh, 0.f);
  r0.z = fmaxf(__uint_as_float(v.y << 16)          * sc + sh, 0.f);
  r0.w = fmaxf(__uint_as_float(v.y & 0xFFFF0000u)  * sc + sh, 0.f);
  r1.x = fmaxf(__uint_as_float(v.z << 16)          * sc + sh, 0.f);
  r1.y = fmaxf(__uint_as_float(v.z & 0xFFFF0000u)  * sc + sh, 0.f);
  r1.z = fmaxf(__uint_as_float(v.w << 16)          * sc + sh, 0.f);
  r1.w = fmaxf(__uint_as_float(v.w & 0xFFFF0000u)  * sc + sh, 0.f);
  *(float4*)(out + e)     = r0;
  *(float4*)(out + e + 4) = r1;
}

extern "C" void kernel_launch(void* const* d_in, const int* in_sizes, int n_in,
                              void* d_out, int out_size, void* d_ws, size_t ws_size,
                              hipStream_t stream){
  const float* x     = (const float*)d_in[0];
  const float* w_off = (const float*)d_in[1];
  const float* b_off = (const float*)d_in[2];
  const float* w     = (const float*)d_in[3];
  const float* gamma = (const float*)d_in[4];
  const float* beta  = (const float*)d_in[5];
  float* out = (float*)d_out;

  char* p = (char*)d_ws;
  ushort* xtp  = (ushort*)p; p += (size_t)Bb * PHW * Cin * 2;     // 17.31 MB (bf16)
  ushort* w2   = (ushort*)p; p += (size_t)Oout * CKd * 2;         // 1.18 MB (bf16)
  ushort* w2of = (ushort*)p; p += (size_t)32 * CKd * 2;           // 0.15 MB (bf16)
  int4*   pidx = (int4*)p;   p += (size_t)Bb * 9 * HWs * 16;      // 4.72 MB
  float4* pwt  = (float4*)p; p += (size_t)Bb * 9 * HWs * 16;      // 4.72 MB
  float*  parts= (float*)p;  p += (size_t)2 * 1024 * 256 * 4;     // 2.10 MB
  float*  stats= (float*)p;  p += 4096;                           // 4 KB
  ushort* outb = (ushort*)p; p += (size_t)Bb * Oout * HWs * 2;    // 16.78 MB (optional)
  size_t need = (size_t)(p - (char*)d_ws);

  k_transpose<<<dim3(2048), dim3(256), 0, stream>>>(x, xtp);
  k_border   <<<dim3(1032), dim3(64),  0, stream>>>(xtp);
  k_wprep    <<<dim3(2592), dim3(256), 0, stream>>>(w, w_off, w2, w2of);
  k_offconv  <<<dim3(512),  dim3(512), 0, stream>>>(xtp, w2of, b_off, pidx, pwt);
  if (ws_size >= need){
    k_main<1>  <<<dim3(512),  dim3(1024), 0, stream>>>(xtp, w2, pidx, pwt, (void*)outb, parts);
    k_bnstats  <<<dim3(256),  dim3(256), 0, stream>>>(parts, stats);
    k_bnapply_b<<<dim3(4096), dim3(256), 0, stream>>>(outb, out, stats, gamma, beta);
  } else {
    k_main<0>  <<<dim3(512),  dim3(1024), 0, stream>>>(xtp, w2, pidx, pwt, (void*)out, parts);
    k_bnstats  <<<dim3(256),  dim3(256), 0, stream>>>(parts, stats);
    k_bnapply  <<<dim3(8192), dim3(256), 0, stream>>>(out, stats, gamma, beta);
  }
}

// Round 16
// 124.527 us; speedup vs baseline: 1.1657x; 1.1657x over previous
//
#include <hip/hip_runtime.h>
#include <hip/hip_bf16.h>

#define HWs   16384
#define Wimg  128
#define Himg  128
#define PW    130
#define PHW   16900      // 130*130 padded pixels
#define Cin   256
#define Oout  256
#define CKd   2304
#define Bb    2

typedef short   bf16x8 __attribute__((ext_vector_type(8)));
typedef float   f32x4  __attribute__((ext_vector_type(4)));
typedef float   f32x2  __attribute__((ext_vector_type(2)));

__device__ __forceinline__ ushort f2bf(float f){
  union { float f; unsigned int i; } v; v.f = f;
  return (ushort)((v.i + 0x8000u) >> 16);
}
__device__ __forceinline__ unsigned cvt_pk_bf16(float lo, float hi){
  unsigned r;
  asm("v_cvt_pk_bf16_f32 %0, %1, %2" : "=v"(r) : "v"(lo), "v"(hi));
  return r;
}
__device__ __forceinline__ void gload_lds16(const ushort* g, void* l){
  __builtin_amdgcn_global_load_lds(
      (const __attribute__((address_space(1))) unsigned int*)g,
      (__attribute__((address_space(3))) unsigned int*)l, 16, 0, 0);
}

// ---------------- x [B,C,H,W] fp32 -> xtp [B][130*130][C] bf16 (interior), vectorized ----------------
__global__ __launch_bounds__(256) void k_transpose(const float* __restrict__ x,
                                                   ushort* __restrict__ xtp){
  int bx = blockIdx.x;                 // 2048
  int b  = bx >> 10;
  int r  = bx & 1023;
  int ct = r >> 8;
  int pt = r & 255;
  int c0 = ct * 64, p0 = pt * 64;
  __shared__ float tile[64][65];
  const float* xb = x + (size_t)b * Cin * HWs;
  int t = threadIdx.x;
  #pragma unroll
  for (int pass = 0; pass < 4; ++pass){
    int idx = pass * 256 + t;          // 0..1023 : 64 rows x 16 float4 cols
    int cl = idx >> 4, pg = idx & 15;
    float4 v = *(const float4*)(xb + (size_t)(c0 + cl) * HWs + p0 + pg * 4);
    tile[cl][pg * 4 + 0] = v.x; tile[cl][pg * 4 + 1] = v.y;
    tile[cl][pg * 4 + 2] = v.z; tile[cl][pg * 4 + 3] = v.w;
  }
  __syncthreads();
  ushort* xo = xtp + (size_t)b * PHW * Cin;
  #pragma unroll
  for (int pass = 0; pass < 4; ++pass){
    int idx = pass * 256 + t;          // 64 px x 16 channel-quads
    int pl = idx >> 4, cc = idx & 15;
    int hw = p0 + pl; int y = hw >> 7, xc = hw & 127;
    unsigned u0 = f2bf(tile[cc * 4 + 0][pl]);
    unsigned u1 = f2bf(tile[cc * 4 + 1][pl]);
    unsigned u2 = f2bf(tile[cc * 4 + 2][pl]);
    unsigned u3 = f2bf(tile[cc * 4 + 3][pl]);
    uint2 pk; pk.x = u0 | (u1 << 16); pk.y = u2 | (u3 << 16);
    *(uint2*)(xo + (size_t)((y + 1) * PW + xc + 1) * Cin + c0 + cc * 4) = pk;
  }
}

// ---------------- zero the padded border ----------------
__global__ __launch_bounds__(64) void k_border(ushort* __restrict__ xtp){
  int e = blockIdx.x;                  // 2 * 516
  int b = e / 516, p = e % 516;
  int y, xc;
  if (p < 130)      { y = 0;       xc = p; }
  else if (p < 260) { y = 129;     xc = p - 130; }
  else if (p < 388) { y = p - 259; xc = 0; }
  else              { y = p - 387; xc = 129; }
  uint2* dst = (uint2*)(xtp + ((size_t)b * PHW + y * PW + xc) * Cin) + threadIdx.x;
  *dst = make_uint2(0u, 0u);
}

// ---------------- weights -> k-major bf16: w2 [256][2304], w2of [32][2304] ----------------
__global__ __launch_bounds__(256) void k_wprep(const float* __restrict__ w,
                                               const float* __restrict__ wof,
                                               ushort* __restrict__ w2,
                                               ushort* __restrict__ w2of){
  int idx = blockIdx.x * 256 + threadIdx.x;    // 2592*256
  if (idx < Oout * CKd){
    int o = idx / CKd, r = idx % CKd;
    int k = r >> 8, c = r & 255;
    w2[idx] = f2bf(w[(size_t)(o * Cin + c) * 9 + k]);
  } else {
    int j = idx - Oout * CKd;
    int o = j / CKd, r = j % CKd;
    int k = r >> 8, c = r & 255;
    float v = (o < 18) ? wof[(size_t)(o * Cin + c) * 9 + k] : 0.f;
    w2of[j] = f2bf(v);
  }
}

// ---------------- offset conv (M=32 bf16 MFMA, BN=64, dbuf) + fused prep ----------------
// pw stores SEPARABLE masked weights: (wy0m, wy1m, wx0m, wx1m)
__global__ __launch_bounds__(512, 4) void k_offconv(const ushort* __restrict__ xtp,
                                                    const ushort* __restrict__ w2of,
                                                    const float* __restrict__ b_off,
                                                    int4* __restrict__ pidx,
                                                    float4* __restrict__ pw){
  int bx = blockIdx.x;                          // 512
  int blkm = ((bx & 7) << 6) | (bx >> 3);       // XCD-chunked swizzle
  int b = blkm >> 8, tile = blkm & 255;
  int hw0 = tile * 64;
  int iy = tile >> 1, jx0 = (tile & 1) * 64;
  __shared__ __align__(16) ushort aw[2][2048];
  __shared__ __align__(16) ushort bv_s[2][4096];
  __shared__ float offs_lds[18][64];
  int t = threadIdx.x, lane = t & 63, wid = t >> 6;
  int mi = wid >> 2, ni = wid & 3;
  f32x4 acc = (f32x4){0,0,0,0};
  const ushort* xb = xtp + (size_t)b * PHW * Cin;

#define OSTAGE(S, P) \
  if ((S) < 36){ int kks = (S) * 64, kt = (S) >> 2, c0s = ((S) * 64) & 255; \
    int dy = kt / 3 - 1, dxx = kt % 3 - 1; \
    if (wid < 4){ int L = t * 16; int oo = L >> 7; int inb = (L & 127) ^ ((oo & 7) << 4); \
      gload_lds16(w2of + (size_t)oo * CKd + kks + (inb >> 1), (char*)aw[P] + L); } \
    { int L = t * 16; int hw_l = L >> 7; int inb = (L & 127) ^ ((hw_l & 7) << 4); \
      int row = (iy + dy + 1) * PW + (jx0 + hw_l + dxx + 1); \
      gload_lds16(xb + (size_t)row * Cin + c0s + (inb >> 1), (char*)bv_s[P] + L); } }

  OSTAGE(0, 0);
  __syncthreads();
  #pragma unroll 1
  for (int step = 0; step < 36; ++step){
    int P = step & 1;
    OSTAGE(step + 1, P ^ 1);
    #pragma unroll
    for (int kk2 = 0; kk2 < 2; ++kk2){
      int coff = kk2 * 64 + ((lane >> 4) << 4);
      bf16x8 a0, bb;
      { int r = mi * 16 + (lane & 15); int byte = r * 128 + coff; byte ^= ((r & 7) << 4); a0 = *(const bf16x8*)((char*)aw[P] + byte); }
      { int r = ni * 16 + (lane & 15); int byte = r * 128 + coff; byte ^= ((r & 7) << 4); bb = *(const bf16x8*)((char*)bv_s[P] + byte); }
      acc = __builtin_amdgcn_mfma_f32_16x16x32_bf16(a0, bb, acc, 0, 0, 0);
    }
    __syncthreads();
  }
#undef OSTAGE
  {
    int hw_l = ni * 16 + (lane & 15);
    #pragma unroll
    for (int r = 0; r < 4; ++r){
      int o = mi * 16 + ((lane >> 4) << 2) + r;
      if (o < 18) offs_lds[o][hw_l] = acc[r] + b_off[o];
    }
  }
  __syncthreads();
  for (int idx = t; idx < 9 * 64; idx += 512){
    int k = idx >> 6, jl = idx & 63;
    int hw = hw0 + jl;
    int i = hw >> 7, jcol = hw & 127;
    float offy = offs_lds[2 * k][jl];
    float offx = offs_lds[2 * k + 1][jl];
    float py = (float)i    + (float)(k / 3 - 1) + offy;
    float px = (float)jcol + (float)(k % 3 - 1) + offx;
    float y0f = floorf(py), x0f = floorf(px);
    float ly = py - y0f, lx = px - x0f;
    int y0 = (int)y0f, x0 = (int)x0f;
    int y1 = y0 + 1, x1 = x0 + 1;
    bool vy0 = (y0 >= 0 && y0 < 128), vy1 = (y1 >= 0 && y1 < 128);
    bool vx0 = (x0 >= 0 && x0 < 128), vx1 = (x1 >= 0 && x1 < 128);
    int iy0 = min(max(y0, 0), 127), iy1 = min(max(y1, 0), 127);
    int ix0 = min(max(x0, 0), 127), ix1 = min(max(x1, 0), 127);
    size_t e = ((size_t)b * 9 + k) * HWs + hw;
    pidx[e] = make_int4(((iy0 + 1) * PW + ix0 + 1) * Cin, ((iy0 + 1) * PW + ix1 + 1) * Cin,
                        ((iy1 + 1) * PW + ix0 + 1) * Cin, ((iy1 + 1) * PW + ix1 + 1) * Cin);
    pw[e]   = make_float4(vy0 ? (1.f - ly) : 0.f, vy1 ? ly : 0.f,
                          vx0 ? (1.f - lx) : 0.f, vx1 ? lx : 0.f);
  }
}

// ---------------- separable bilinear combine: 4 bf16 corner dwords -> packed bf16x2 ----------------
__device__ __forceinline__ f32x2 up2(unsigned d){
  f32x2 r; r.x = __uint_as_float(d << 16); r.y = __uint_as_float(d & 0xFFFF0000u); return r;
}
__device__ __forceinline__ unsigned combine_pair(unsigned d00, unsigned d01, unsigned d10, unsigned d11,
                                                 float4 wt){   // wt = (wy0m, wy1m, wx0m, wx1m)
  f32x2 t0 = wt.z * up2(d00) + wt.w * up2(d01);
  f32x2 t1 = wt.z * up2(d10) + wt.w * up2(d11);
  f32x2 e  = wt.x * t0 + wt.y * t1;
  return cvt_pk_bf16(e.x, e.y);
}

// ---------------- fused gather + main GEMM (r14 structure + hoisted LDS addressing) ----------------
template<int BF16OUT>
__global__ __launch_bounds__(1024, 4) void k_main(const ushort* __restrict__ xtp,
                                                  const ushort* __restrict__ w2,
                                                  const int4* __restrict__ pidx,
                                                  const float4* __restrict__ pw,
                                                  void* __restrict__ outp,
                                                  float* __restrict__ partials){
  int bx = blockIdx.x;                          // 256
  int blkm = ((bx & 7) << 5) | (bx >> 3);       // XCD-chunked swizzle
  int b = blkm >> 7, tile = blkm & 127;
  int hw0 = tile * 128;
  __shared__ __align__(16) ushort smem[49152];  // 96KB: A dbuf 2x32KB, B dbuf 2x16KB
  ushort* Ab0 = smem;
  ushort* Ab1 = smem + 16384;
  ushort* Bb0 = smem + 32768;
  ushort* Bb1 = smem + 40960;
  int t = threadIdx.x, lane = t & 63, wid = t >> 6;  // 16 waves
  int wm = wid >> 2, wn = wid & 3;              // 4x4 wave grid: 64o x 32hw each
  int cg = t & 7, hl = t >> 3;                  // B staging coords: hl 0..127
  f32x4 acc[4][2];
  #pragma unroll
  for (int mi = 0; mi < 4; ++mi)
    #pragma unroll
    for (int ni = 0; ni < 2; ++ni) acc[mi][ni] = (f32x4){0,0,0,0};
  const ushort* xb  = xtp  + (size_t)b * PHW * Cin;
  const int4*   pib = pidx + (size_t)b * 9 * HWs + hw0;
  const float4* pwb = pw   + (size_t)b * 9 * HWs + hw0;

  // Hoisted LDS fragment addressing. Identity: coff<128, swz bits 4..6, r*128 bits>=7
  //   (r*128 + coff) ^ swz == r*128 | (coff ^ swz)
  int csel = (lane >> 4) << 4;
  int rowa[4], swza[4], rowb[2], swzb[2];
  #pragma unroll
  for (int mi = 0; mi < 4; ++mi){
    int r = wm * 64 + mi * 16 + (lane & 15);
    rowa[mi] = r * 128; swza[mi] = (r & 7) << 4;
  }
  #pragma unroll
  for (int ni = 0; ni < 2; ++ni){
    int r = wn * 32 + ni * 16 + (lane & 15);
    rowb[ni] = r * 128; swzb[ni] = (r & 7) << 4;
  }
  const int wbyte = (hl * 128 + cg * 16) ^ ((hl & 7) << 4);   // B staging write offset

  int4   ids[2];               // [parity], pre-scaled by Cin
  float4 wts[2];
  uint4  g[2][4];              // [parity][corner]

#define IDSLOAD(P, S) \
  if ((S) < 36){ int kq = (S) >> 2; \
    ids[P] = pib[(size_t)kq * HWs + hl]; }

#define CORNERS(P, S) \
  if ((S) < 36){ int cb = (((S) * 64) & 255) + cg * 8; int kq = (S) >> 2; \
    wts[P] = pwb[(size_t)kq * HWs + hl]; \
    g[P][0] = *(const uint4*)(xb + ids[P].x + cb); \
    g[P][1] = *(const uint4*)(xb + ids[P].y + cb); \
    g[P][2] = *(const uint4*)(xb + ids[P].z + cb); \
    g[P][3] = *(const uint4*)(xb + ids[P].w + cb); }

#define STAGEA(S, ABP) \
  if ((S) < 36){ int kks = (S) * 64; \
    _Pragma("unroll") for (int h2 = 0; h2 < 2; ++h2){ \
      int L = (wid * 2 + h2) * 1024 + lane * 16; \
      int oo = L >> 7; int inb = (L & 127) ^ ((oo & 7) << 4); \
      gload_lds16(w2 + (size_t)oo * CKd + kks + (inb >> 1), (char*)(ABP) + L); } }

#define COMBINE(P, S, BBP) \
  if ((S) < 36){ \
    float4 wtv = wts[P]; \
    uint4 ov; \
    ov.x = combine_pair(g[P][0].x, g[P][1].x, g[P][2].x, g[P][3].x, wtv); \
    ov.y = combine_pair(g[P][0].y, g[P][1].y, g[P][2].y, g[P][3].y, wtv); \
    ov.z = combine_pair(g[P][0].z, g[P][1].z, g[P][2].z, g[P][3].z, wtv); \
    ov.w = combine_pair(g[P][0].w, g[P][1].w, g[P][2].w, g[P][3].w, wtv); \
    *(uint4*)((char*)(BBP) + wbyte) = ov; }

#define MFMA_PHASE(ABP, BBP) \
  { __builtin_amdgcn_s_setprio(1); \
    _Pragma("unroll") for (int kk2 = 0; kk2 < 2; ++kk2){ \
      int coff = kk2 * 64 + csel; \
      bf16x8 a[4], bv[2]; \
      _Pragma("unroll") for (int mi = 0; mi < 4; ++mi) \
        a[mi] = *(const bf16x8*)((const char*)(ABP) + (rowa[mi] | (coff ^ swza[mi]))); \
      _Pragma("unroll") for (int ni = 0; ni < 2; ++ni) \
        bv[ni] = *(const bf16x8*)((const char*)(BBP) + (rowb[ni] | (coff ^ swzb[ni]))); \
      _Pragma("unroll") for (int mi = 0; mi < 4; ++mi) \
        _Pragma("unroll") for (int ni = 0; ni < 2; ++ni) \
          acc[mi][ni] = __builtin_amdgcn_mfma_f32_16x16x32_bf16(a[mi], bv[ni], acc[mi][ni], 0, 0, 0); } \
    __builtin_amdgcn_s_setprio(0); }

  // ---- prologue: corners(0),(1) in flight; A(0),B(0) staged ----
  IDSLOAD(0, 0);
  IDSLOAD(1, 1);
  CORNERS(0, 0);
  IDSLOAD(0, 2);
  CORNERS(1, 1);
  IDSLOAD(1, 3);
  STAGEA(0, Ab0);
  COMBINE(0, 0, Bb0);
  __syncthreads();

  // ---- main loop: phase T computes tile T; corners issued 2 ahead ----
  #pragma unroll 1
  for (int tt = 0; tt < 36; tt += 2){
    // even phase T=tt
    CORNERS(0, tt + 2);
    STAGEA(tt + 1, Ab1);
    IDSLOAD(0, tt + 4);
    MFMA_PHASE(Ab0, Bb0);
    COMBINE(1, tt + 1, Bb1);
    __syncthreads();
    // odd phase T=tt+1
    CORNERS(1, tt + 3);
    STAGEA(tt + 2, Ab0);
    IDSLOAD(1, tt + 5);
    MFMA_PHASE(Ab1, Bb1);
    COMBINE(0, tt + 2, Bb0);
    __syncthreads();
  }
#undef IDSLOAD
#undef CORNERS
#undef STAGEA
#undef COMBINE
#undef MFMA_PHASE

  // epilogue: C write (fp32 or bf16) + BN partial sums
  #pragma unroll
  for (int mi = 0; mi < 4; ++mi){
    int obase = wm * 64 + mi * 16 + ((lane >> 4) << 2);
    #pragma unroll
    for (int ni = 0; ni < 2; ++ni){
      int hw = hw0 + wn * 32 + ni * 16 + (lane & 15);
      if (BF16OUT){
        ushort* ob = (ushort*)outp + ((size_t)b * Oout + obase) * HWs + hw;
        #pragma unroll
        for (int r = 0; r < 4; ++r) ob[(size_t)r * HWs] = f2bf(acc[mi][ni][r]);
      } else {
        float* op = (float*)outp + ((size_t)b * Oout + obase) * HWs + hw;
        #pragma unroll
        for (int r = 0; r < 4; ++r) op[(size_t)r * HWs] = acc[mi][ni][r];
      }
    }
  }
  #pragma unroll
  for (int mi = 0; mi < 4; ++mi){
    #pragma unroll
    for (int r = 0; r < 4; ++r){
      float s = 0.f, s2 = 0.f;
      #pragma unroll
      for (int ni = 0; ni < 2; ++ni){ float v = acc[mi][ni][r]; s += v; s2 += v * v; }
      #pragma unroll
      for (int off2 = 1; off2 < 16; off2 <<= 1){
        s  += __shfl_xor(s, off2);
        s2 += __shfl_xor(s2, off2);
      }
      if ((lane & 15) == 0){
        int o = wm * 64 + mi * 16 + ((lane >> 4) << 2) + r;
        int row = blkm * 4 + wn;                 // 0..1023
        partials[(size_t)row * 256 + o] = s;
        partials[(size_t)1024 * 256 + (size_t)row * 256 + o] = s2;
      }
    }
  }
}

// ---------------- BN stats from partials ----------------
__global__ __launch_bounds__(256) void k_bnstats(const float* __restrict__ partials,
                                                 float* __restrict__ stats){
  int o = blockIdx.x, t = threadIdx.x;
  float s = 0.f, s2 = 0.f;
  for (int i = t; i < 1024; i += 256){
    s  += partials[(size_t)i * 256 + o];
    s2 += partials[(size_t)1024 * 256 + (size_t)i * 256 + o];
  }
  #pragma unroll
  for (int off = 32; off > 0; off >>= 1){
    s  += __shfl_down(s, off);
    s2 += __shfl_down(s2, off);
  }
  __shared__ float rs[4], rs2[4];
  int lane = t & 63, w = t >> 6;
  if (lane == 0){ rs[w] = s; rs2[w] = s2; }
  __syncthreads();
  if (t == 0){
    float S = 0.f, S2 = 0.f;
    for (int i = 0; i < 4; ++i){ S += rs[i]; S2 += rs2[i]; }
    float mean = S / 32768.f;
    float var  = S2 / 32768.f - mean * mean;
    stats[o] = mean;
    stats[256 + o] = rsqrtf(var + 1e-5f);
  }
}

// ---------------- normalize + ReLU: fp32 in-place (fallback) ----------------
__global__ __launch_bounds__(256) void k_bnapply(float* __restrict__ out,
                                                 const float* __restrict__ stats,
                                                 const float* __restrict__ gamma,
                                                 const float* __restrict__ beta){
  size_t e = ((size_t)blockIdx.x * 256 + threadIdx.x) * 4;
  int o = (int)((e >> 14) & 255);
  float mean = stats[o], rstd = stats[256 + o];
  float sc = rstd * gamma[o];
  float sh = beta[o] - mean * sc;
  float4 v = *(float4*)(out + e);
  v.x = fmaxf(v.x * sc + sh, 0.f);
  v.y = fmaxf(v.y * sc + sh, 0.f);
  v.z = fmaxf(v.z * sc + sh, 0.f);
  v.w = fmaxf(v.w * sc + sh, 0.f);
  *(float4*)(out + e) = v;
}

// ---------------- normalize + ReLU: bf16 -> fp32 ----------------
__global__ __launch_bounds__(256) void k_bnapply_b(const ushort* __restrict__ outb,
                                                   float* __restrict__ out,
                                                   const float* __restrict__ stats,
                                                   const float* __restrict__ gamma,
                                                   const float* __restrict__ beta){
  size_t e = ((size_t)blockIdx.x * 256 + threadIdx.x) * 8;   // 4096 blocks
  int o = (int)((e >> 14) & 255);
  float mean = stats[o], rstd = stats[256 + o];
  float sc = rstd * gamma[o];
  float sh = beta[o] - mean * sc;
  uint4 v = *(const uint4*)(outb + e);
  float4 r0, r1;
  r0.x = fmaxf(__uint_as_float(v.x << 16)          * sc + sh, 0.f);
  r0.y = fmaxf(__uint_as_float(v.x & 0xFFFF0000u)  * sc + sh, 0.f);
  r0.z = fmaxf(__uint_as_float(v.y << 16)          * sc + sh, 0.f);
  r0.w = fmaxf(__uint_as_float(v.y & 0xFFFF0000u)  * sc + sh, 0.f);
  r1.x = fmaxf(__uint_as_float(v.z << 16)          * sc + sh, 0.f);
  r1.y = fmaxf(__uint_as_float(v.z & 0xFFFF0000u)  * sc + sh, 0.f);
  r1.z = fmaxf(__uint_as_float(v.w << 16)          * sc + sh, 0.f);
  r1.w = fmaxf(__uint_as_float(v.w & 0xFFFF0000u)  * sc + sh, 0.f);
  *(float4*)(out + e)     = r0;
  *(float4*)(out + e + 4) = r1;
}

extern "C" void kernel_launch(void* const* d_in, const int* in_sizes, int n_in,
                              void* d_out, int out_size, void* d_ws, size_t ws_size,
                              hipStream_t stream){
  const float* x     = (const float*)d_in[0];
  const float* w_off = (const float*)d_in[1];
  const float* b_off = (const float*)d_in[2];
  const float* w     = (const float*)d_in[3];
  const float* gamma = (const float*)d_in[4];
  const float* beta  = (const float*)d_in[5];
  float* out = (float*)d_out;

  char* p = (char*)d_ws;
  ushort* xtp  = (ushort*)p; p += (size_t)Bb * PHW * Cin * 2;     // 17.31 MB (bf16)
  ushort* w2   = (ushort*)p; p += (size_t)Oout * CKd * 2;         // 1.18 MB (bf16)
  ushort* w2of = (ushort*)p; p += (size_t)32 * CKd * 2;           // 0.15 MB (bf16)
  int4*   pidx = (int4*)p;   p += (size_t)Bb * 9 * HWs * 16;      // 4.72 MB
  float4* pwt  = (float4*)p; p += (size_t)Bb * 9 * HWs * 16;      // 4.72 MB
  float*  parts= (float*)p;  p += (size_t)2 * 1024 * 256 * 4;     // 2.10 MB
  float*  stats= (float*)p;  p += 4096;                           // 4 KB
  ushort* outb = (ushort*)p; p += (size_t)Bb * Oout * HWs * 2;    // 16.78 MB (optional)
  size_t need = (size_t)(p - (char*)d_ws);

  k_transpose<<<dim3(2048), dim3(256), 0, stream>>>(x, xtp);
  k_border   <<<dim3(1032), dim3(64),  0, stream>>>(xtp);
  k_wprep    <<<dim3(2592), dim3(256), 0, stream>>>(w, w_off, w2, w2of);
  k_offconv  <<<dim3(512),  dim3(512), 0, stream>>>(xtp, w2of, b_off, pidx, pwt);
  if (ws_size >= need){
    k_main<1>  <<<dim3(256),  dim3(1024), 0, stream>>>(xtp, w2, pidx, pwt, (void*)outb, parts);
    k_bnstats  <<<dim3(256),  dim3(256), 0, stream>>>(parts, stats);
    k_bnapply_b<<<dim3(4096), dim3(256), 0, stream>>>(outb, out, stats, gamma, beta);
  } else {
    k_main<0>  <<<dim3(256),  dim3(1024), 0, stream>>>(xtp, w2, pidx, pwt, (void*)out, parts);
    k_bnstats  <<<dim3(256),  dim3(256), 0, stream>>>(parts, stats);
    k_bnapply  <<<dim3(8192), dim3(256), 0, stream>>>(out, stats, gamma, beta);
  }
}

// Round 17
// 120.442 us; speedup vs baseline: 1.2053x; 1.0339x over previous
//
#include <hip/hip_runtime.h>
#include <hip/hip_bf16.h>

#define HWs   16384
#define Wimg  128
#define Himg  128
#define PW    130
#define PHW   16900      // 130*130 padded pixels
#define Cin   256
#define Oout  256
#define CKd   2304
#define Bb    2

typedef short   bf16x8 __attribute__((ext_vector_type(8)));
typedef float   f32x4  __attribute__((ext_vector_type(4)));
typedef float   f32x2  __attribute__((ext_vector_type(2)));

__device__ __forceinline__ ushort f2bf(float f){
  union { float f; unsigned int i; } v; v.f = f;
  return (ushort)((v.i + 0x8000u) >> 16);
}
__device__ __forceinline__ unsigned cvt_pk_bf16(float lo, float hi){
  unsigned r;
  asm("v_cvt_pk_bf16_f32 %0, %1, %2" : "=v"(r) : "v"(lo), "v"(hi));
  return r;
}
__device__ __forceinline__ void gload_lds16(const ushort* g, void* l){
  __builtin_amdgcn_global_load_lds(
      (const __attribute__((address_space(1))) unsigned int*)g,
      (__attribute__((address_space(3))) unsigned int*)l, 16, 0, 0);
}

// ---------------- fused prep: transpose (2048 blk) + border (258 blk) + wprep (2592 blk) ----------------
__global__ __launch_bounds__(256) void k_prep_all(const float* __restrict__ x,
                                                  const float* __restrict__ w,
                                                  const float* __restrict__ wof,
                                                  ushort* __restrict__ xtp,
                                                  ushort* __restrict__ w2,
                                                  ushort* __restrict__ w2of){
  int bx = blockIdx.x;
  int t  = threadIdx.x;
  if (bx < 2048){
    // ---- transpose x[B,C,H,W] fp32 -> xtp[B][130*130][C] bf16 (interior), vectorized ----
    int b  = bx >> 10;
    int r  = bx & 1023;
    int ct = r >> 8;
    int pt = r & 255;
    int c0 = ct * 64, p0 = pt * 64;
    __shared__ float tile[64][65];
    const float* xb = x + (size_t)b * Cin * HWs;
    #pragma unroll
    for (int pass = 0; pass < 4; ++pass){
      int idx = pass * 256 + t;          // 64 rows x 16 float4 cols
      int cl = idx >> 4, pg = idx & 15;
      float4 v = *(const float4*)(xb + (size_t)(c0 + cl) * HWs + p0 + pg * 4);
      tile[cl][pg * 4 + 0] = v.x; tile[cl][pg * 4 + 1] = v.y;
      tile[cl][pg * 4 + 2] = v.z; tile[cl][pg * 4 + 3] = v.w;
    }
    __syncthreads();
    ushort* xo = xtp + (size_t)b * PHW * Cin;
    #pragma unroll
    for (int pass = 0; pass < 4; ++pass){
      int idx = pass * 256 + t;          // 64 px x 16 channel-quads
      int pl = idx >> 4, cc = idx & 15;
      int hw = p0 + pl; int y = hw >> 7, xc = hw & 127;
      unsigned u0 = f2bf(tile[cc * 4 + 0][pl]);
      unsigned u1 = f2bf(tile[cc * 4 + 1][pl]);
      unsigned u2 = f2bf(tile[cc * 4 + 2][pl]);
      unsigned u3 = f2bf(tile[cc * 4 + 3][pl]);
      uint2 pk; pk.x = u0 | (u1 << 16); pk.y = u2 | (u3 << 16);
      *(uint2*)(xo + (size_t)((y + 1) * PW + xc + 1) * Cin + c0 + cc * 4) = pk;
    }
  } else if (bx < 2048 + 258){
    // ---- zero the padded border: 1032 segments, 4 per block ----
    int e = (bx - 2048) * 4 + (t >> 6);
    int lane = t & 63;
    if (e < 2 * 516){
      int b = e / 516, p = e % 516;
      int y, xc;
      if (p < 130)      { y = 0;       xc = p; }
      else if (p < 260) { y = 129;     xc = p - 130; }
      else if (p < 388) { y = p - 259; xc = 0; }
      else              { y = p - 387; xc = 129; }
      uint2* dst = (uint2*)(xtp + ((size_t)b * PHW + y * PW + xc) * Cin) + lane;
      *dst = make_uint2(0u, 0u);
    }
  } else {
    // ---- weights -> k-major bf16 ----
    int idx = (bx - 2048 - 258) * 256 + t;     // 2592*256
    if (idx < Oout * CKd){
      int o = idx / CKd, r = idx % CKd;
      int k = r >> 8, c = r & 255;
      w2[idx] = f2bf(w[(size_t)(o * Cin + c) * 9 + k]);
    } else {
      int j = idx - Oout * CKd;
      int o = j / CKd, r = j % CKd;
      int k = r >> 8, c = r & 255;
      float v = (o < 18) ? wof[(size_t)(o * Cin + c) * 9 + k] : 0.f;
      w2of[j] = f2bf(v);
    }
  }
}

// ---------------- offset conv (M=32 bf16 MFMA, BN=64, dbuf) + fused prep ----------------
// pw stores SEPARABLE masked weights: (wy0m, wy1m, wx0m, wx1m)
__global__ __launch_bounds__(512, 4) void k_offconv(const ushort* __restrict__ xtp,
                                                    const ushort* __restrict__ w2of,
                                                    const float* __restrict__ b_off,
                                                    int4* __restrict__ pidx,
                                                    float4* __restrict__ pw){
  int bx = blockIdx.x;                          // 512
  int blkm = ((bx & 7) << 6) | (bx >> 3);       // XCD-chunked swizzle
  int b = blkm >> 8, tile = blkm & 255;
  int hw0 = tile * 64;
  int iy = tile >> 1, jx0 = (tile & 1) * 64;
  __shared__ __align__(16) ushort aw[2][2048];
  __shared__ __align__(16) ushort bv_s[2][4096];
  __shared__ float offs_lds[18][64];
  int t = threadIdx.x, lane = t & 63, wid = t >> 6;
  int mi = wid >> 2, ni = wid & 3;
  f32x4 acc = (f32x4){0,0,0,0};
  const ushort* xb = xtp + (size_t)b * PHW * Cin;

#define OSTAGE(S, P) \
  if ((S) < 36){ int kks = (S) * 64, kt = (S) >> 2, c0s = ((S) * 64) & 255; \
    int dy = kt / 3 - 1, dxx = kt % 3 - 1; \
    if (wid < 4){ int L = t * 16; int oo = L >> 7; int inb = (L & 127) ^ ((oo & 7) << 4); \
      gload_lds16(w2of + (size_t)oo * CKd + kks + (inb >> 1), (char*)aw[P] + L); } \
    { int L = t * 16; int hw_l = L >> 7; int inb = (L & 127) ^ ((hw_l & 7) << 4); \
      int row = (iy + dy + 1) * PW + (jx0 + hw_l + dxx + 1); \
      gload_lds16(xb + (size_t)row * Cin + c0s + (inb >> 1), (char*)bv_s[P] + L); } }

  OSTAGE(0, 0);
  __syncthreads();
  #pragma unroll 1
  for (int step = 0; step < 36; ++step){
    int P = step & 1;
    OSTAGE(step + 1, P ^ 1);
    #pragma unroll
    for (int kk2 = 0; kk2 < 2; ++kk2){
      int coff = kk2 * 64 + ((lane >> 4) << 4);
      bf16x8 a0, bb;
      { int r = mi * 16 + (lane & 15); int byte = r * 128 + coff; byte ^= ((r & 7) << 4); a0 = *(const bf16x8*)((char*)aw[P] + byte); }
      { int r = ni * 16 + (lane & 15); int byte = r * 128 + coff; byte ^= ((r & 7) << 4); bb = *(const bf16x8*)((char*)bv_s[P] + byte); }
      acc = __builtin_amdgcn_mfma_f32_16x16x32_bf16(a0, bb, acc, 0, 0, 0);
    }
    __syncthreads();
  }
#undef OSTAGE
  {
    int hw_l = ni * 16 + (lane & 15);
    #pragma unroll
    for (int r = 0; r < 4; ++r){
      int o = mi * 16 + ((lane >> 4) << 2) + r;
      if (o < 18) offs_lds[o][hw_l] = acc[r] + b_off[o];
    }
  }
  __syncthreads();
  for (int idx = t; idx < 9 * 64; idx += 512){
    int k = idx >> 6, jl = idx & 63;
    int hw = hw0 + jl;
    int i = hw >> 7, jcol = hw & 127;
    float offy = offs_lds[2 * k][jl];
    float offx = offs_lds[2 * k + 1][jl];
    float py = (float)i    + (float)(k / 3 - 1) + offy;
    float px = (float)jcol + (float)(k % 3 - 1) + offx;
    float y0f = floorf(py), x0f = floorf(px);
    float ly = py - y0f, lx = px - x0f;
    int y0 = (int)y0f, x0 = (int)x0f;
    int y1 = y0 + 1, x1 = x0 + 1;
    bool vy0 = (y0 >= 0 && y0 < 128), vy1 = (y1 >= 0 && y1 < 128);
    bool vx0 = (x0 >= 0 && x0 < 128), vx1 = (x1 >= 0 && x1 < 128);
    int iy0 = min(max(y0, 0), 127), iy1 = min(max(y1, 0), 127);
    int ix0 = min(max(x0, 0), 127), ix1 = min(max(x1, 0), 127);
    size_t e = ((size_t)b * 9 + k) * HWs + hw;
    pidx[e] = make_int4(((iy0 + 1) * PW + ix0 + 1) * Cin, ((iy0 + 1) * PW + ix1 + 1) * Cin,
                        ((iy1 + 1) * PW + ix0 + 1) * Cin, ((iy1 + 1) * PW + ix1 + 1) * Cin);
    pw[e]   = make_float4(vy0 ? (1.f - ly) : 0.f, vy1 ? ly : 0.f,
                          vx0 ? (1.f - lx) : 0.f, vx1 ? lx : 0.f);
  }
}

// ---------------- separable bilinear combine: 4 bf16 corner dwords -> packed bf16x2 ----------------
__device__ __forceinline__ f32x2 up2(unsigned d){
  f32x2 r; r.x = __uint_as_float(d << 16); r.y = __uint_as_float(d & 0xFFFF0000u); return r;
}
__device__ __forceinline__ unsigned combine_pair(unsigned d00, unsigned d01, unsigned d10, unsigned d11,
                                                 float4 wt){   // wt = (wy0m, wy1m, wx0m, wx1m)
  f32x2 t0 = wt.z * up2(d00) + wt.w * up2(d01);
  f32x2 t1 = wt.z * up2(d10) + wt.w * up2(d11);
  f32x2 e  = wt.x * t0 + wt.y * t1;
  return cvt_pk_bf16(e.x, e.y);
}

// ---------------- fused gather + main GEMM (r16 structure, unchanged) ----------------
template<int BF16OUT>
__global__ __launch_bounds__(1024, 4) void k_main(const ushort* __restrict__ xtp,
                                                  const ushort* __restrict__ w2,
                                                  const int4* __restrict__ pidx,
                                                  const float4* __restrict__ pw,
                                                  void* __restrict__ outp,
                                                  float* __restrict__ partials){
  int bx = blockIdx.x;                          // 256
  int blkm = ((bx & 7) << 5) | (bx >> 3);       // XCD-chunked swizzle
  int b = blkm >> 7, tile = blkm & 127;
  int hw0 = tile * 128;
  __shared__ __align__(16) ushort smem[49152];  // 96KB: A dbuf 2x32KB, B dbuf 2x16KB
  ushort* Ab0 = smem;
  ushort* Ab1 = smem + 16384;
  ushort* Bb0 = smem + 32768;
  ushort* Bb1 = smem + 40960;
  int t = threadIdx.x, lane = t & 63, wid = t >> 6;  // 16 waves
  int wm = wid >> 2, wn = wid & 3;              // 4x4 wave grid: 64o x 32hw each
  int cg = t & 7, hl = t >> 3;                  // B staging coords: hl 0..127
  f32x4 acc[4][2];
  #pragma unroll
  for (int mi = 0; mi < 4; ++mi)
    #pragma unroll
    for (int ni = 0; ni < 2; ++ni) acc[mi][ni] = (f32x4){0,0,0,0};
  const ushort* xb  = xtp  + (size_t)b * PHW * Cin;
  const int4*   pib = pidx + (size_t)b * 9 * HWs + hw0;
  const float4* pwb = pw   + (size_t)b * 9 * HWs + hw0;

  int csel = (lane >> 4) << 4;
  int rowa[4], swza[4], rowb[2], swzb[2];
  #pragma unroll
  for (int mi = 0; mi < 4; ++mi){
    int r = wm * 64 + mi * 16 + (lane & 15);
    rowa[mi] = r * 128; swza[mi] = (r & 7) << 4;
  }
  #pragma unroll
  for (int ni = 0; ni < 2; ++ni){
    int r = wn * 32 + ni * 16 + (lane & 15);
    rowb[ni] = r * 128; swzb[ni] = (r & 7) << 4;
  }
  const int wbyte = (hl * 128 + cg * 16) ^ ((hl & 7) << 4);

  int4   ids[2];
  float4 wts[2];
  uint4  g[2][4];

#define IDSLOAD(P, S) \
  if ((S) < 36){ int kq = (S) >> 2; \
    ids[P] = pib[(size_t)kq * HWs + hl]; }

#define CORNERS(P, S) \
  if ((S) < 36){ int cb = (((S) * 64) & 255) + cg * 8; int kq = (S) >> 2; \
    wts[P] = pwb[(size_t)kq * HWs + hl]; \
    g[P][0] = *(const uint4*)(xb + ids[P].x + cb); \
    g[P][1] = *(const uint4*)(xb + ids[P].y + cb); \
    g[P][2] = *(const uint4*)(xb + ids[P].z + cb); \
    g[P][3] = *(const uint4*)(xb + ids[P].w + cb); }

#define STAGEA(S, ABP) \
  if ((S) < 36){ int kks = (S) * 64; \
    _Pragma("unroll") for (int h2 = 0; h2 < 2; ++h2){ \
      int L = (wid * 2 + h2) * 1024 + lane * 16; \
      int oo = L >> 7; int inb = (L & 127) ^ ((oo & 7) << 4); \
      gload_lds16(w2 + (size_t)oo * CKd + kks + (inb >> 1), (char*)(ABP) + L); } }

#define COMBINE(P, S, BBP) \
  if ((S) < 36){ \
    float4 wtv = wts[P]; \
    uint4 ov; \
    ov.x = combine_pair(g[P][0].x, g[P][1].x, g[P][2].x, g[P][3].x, wtv); \
    ov.y = combine_pair(g[P][0].y, g[P][1].y, g[P][2].y, g[P][3].y, wtv); \
    ov.z = combine_pair(g[P][0].z, g[P][1].z, g[P][2].z, g[P][3].z, wtv); \
    ov.w = combine_pair(g[P][0].w, g[P][1].w, g[P][2].w, g[P][3].w, wtv); \
    *(uint4*)((char*)(BBP) + wbyte) = ov; }

#define MFMA_PHASE(ABP, BBP) \
  { __builtin_amdgcn_s_setprio(1); \
    _Pragma("unroll") for (int kk2 = 0; kk2 < 2; ++kk2){ \
      int coff = kk2 * 64 + csel; \
      bf16x8 a[4], bv[2]; \
      _Pragma("unroll") for (int mi = 0; mi < 4; ++mi) \
        a[mi] = *(const bf16x8*)((const char*)(ABP) + (rowa[mi] | (coff ^ swza[mi]))); \
      _Pragma("unroll") for (int ni = 0; ni < 2; ++ni) \
        bv[ni] = *(const bf16x8*)((const char*)(BBP) + (rowb[ni] | (coff ^ swzb[ni]))); \
      _Pragma("unroll") for (int mi = 0; mi < 4; ++mi) \
        _Pragma("unroll") for (int ni = 0; ni < 2; ++ni) \
          acc[mi][ni] = __builtin_amdgcn_mfma_f32_16x16x32_bf16(a[mi], bv[ni], acc[mi][ni], 0, 0, 0); } \
    __builtin_amdgcn_s_setprio(0); }

  // ---- prologue ----
  IDSLOAD(0, 0);
  IDSLOAD(1, 1);
  CORNERS(0, 0);
  IDSLOAD(0, 2);
  CORNERS(1, 1);
  IDSLOAD(1, 3);
  STAGEA(0, Ab0);
  COMBINE(0, 0, Bb0);
  __syncthreads();

  // ---- main loop ----
  #pragma unroll 1
  for (int tt = 0; tt < 36; tt += 2){
    CORNERS(0, tt + 2);
    STAGEA(tt + 1, Ab1);
    IDSLOAD(0, tt + 4);
    MFMA_PHASE(Ab0, Bb0);
    COMBINE(1, tt + 1, Bb1);
    __syncthreads();
    CORNERS(1, tt + 3);
    STAGEA(tt + 2, Ab0);
    IDSLOAD(1, tt + 5);
    MFMA_PHASE(Ab1, Bb1);
    COMBINE(0, tt + 2, Bb0);
    __syncthreads();
  }
#undef IDSLOAD
#undef CORNERS
#undef STAGEA
#undef COMBINE
#undef MFMA_PHASE

  // epilogue: C write + BN partial sums
  #pragma unroll
  for (int mi = 0; mi < 4; ++mi){
    int obase = wm * 64 + mi * 16 + ((lane >> 4) << 2);
    #pragma unroll
    for (int ni = 0; ni < 2; ++ni){
      int hw = hw0 + wn * 32 + ni * 16 + (lane & 15);
      if (BF16OUT){
        ushort* ob = (ushort*)outp + ((size_t)b * Oout + obase) * HWs + hw;
        #pragma unroll
        for (int r = 0; r < 4; ++r) ob[(size_t)r * HWs] = f2bf(acc[mi][ni][r]);
      } else {
        float* op = (float*)outp + ((size_t)b * Oout + obase) * HWs + hw;
        #pragma unroll
        for (int r = 0; r < 4; ++r) op[(size_t)r * HWs] = acc[mi][ni][r];
      }
    }
  }
  #pragma unroll
  for (int mi = 0; mi < 4; ++mi){
    #pragma unroll
    for (int r = 0; r < 4; ++r){
      float s = 0.f, s2 = 0.f;
      #pragma unroll
      for (int ni = 0; ni < 2; ++ni){ float v = acc[mi][ni][r]; s += v; s2 += v * v; }
      #pragma unroll
      for (int off2 = 1; off2 < 16; off2 <<= 1){
        s  += __shfl_xor(s, off2);
        s2 += __shfl_xor(s2, off2);
      }
      if ((lane & 15) == 0){
        int o = wm * 64 + mi * 16 + ((lane >> 4) << 2) + r;
        int row = blkm * 4 + wn;                 // 0..1023
        partials[(size_t)row * 256 + o] = s;
        partials[(size_t)1024 * 256 + (size_t)row * 256 + o] = s2;
      }
    }
  }
}

// ---------------- BN stats from partials ----------------
__global__ __launch_bounds__(256) void k_bnstats(const float* __restrict__ partials,
                                                 float* __restrict__ stats){
  int o = blockIdx.x, t = threadIdx.x;
  float s = 0.f, s2 = 0.f;
  for (int i = t; i < 1024; i += 256){
    s  += partials[(size_t)i * 256 + o];
    s2 += partials[(size_t)1024 * 256 + (size_t)i * 256 + o];
  }
  #pragma unroll
  for (int off = 32; off > 0; off >>= 1){
    s  += __shfl_down(s, off);
    s2 += __shfl_down(s2, off);
  }
  __shared__ float rs[4], rs2[4];
  int lane = t & 63, w = t >> 6;
  if (lane == 0){ rs[w] = s; rs2[w] = s2; }
  __syncthreads();
  if (t == 0){
    float S = 0.f, S2 = 0.f;
    for (int i = 0; i < 4; ++i){ S += rs[i]; S2 += rs2[i]; }
    float mean = S / 32768.f;
    float var  = S2 / 32768.f - mean * mean;
    stats[o] = mean;
    stats[256 + o] = rsqrtf(var + 1e-5f);
  }
}

// ---------------- normalize + ReLU: fp32 in-place (fallback) ----------------
__global__ __launch_bounds__(256) void k_bnapply(float* __restrict__ out,
                                                 const float* __restrict__ stats,
                                                 const float* __restrict__ gamma,
                                                 const float* __restrict__ beta){
  size_t e = ((size_t)blockIdx.x * 256 + threadIdx.x) * 4;
  int o = (int)((e >> 14) & 255);
  float mean = stats[o], rstd = stats[256 + o];
  float sc = rstd * gamma[o];
  float sh = beta[o] - mean * sc;
  float4 v = *(float4*)(out + e);
  v.x = fmaxf(v.x * sc + sh, 0.f);
  v.y = fmaxf(v.y * sc + sh, 0.f);
  v.z = fmaxf(v.z * sc + sh, 0.f);
  v.w = fmaxf(v.w * sc + sh, 0.f);
  *(float4*)(out + e) = v;
}

// ---------------- normalize + ReLU: bf16 -> fp32 ----------------
__global__ __launch_bounds__(256) void k_bnapply_b(const ushort* __restrict__ outb,
                                                   float* __restrict__ out,
                                                   const float* __restrict__ stats,
                                                   const float* __restrict__ gamma,
                                                   const float* __restrict__ beta){
  size_t e = ((size_t)blockIdx.x * 256 + threadIdx.x) * 8;   // 4096 blocks
  int o = (int)((e >> 14) & 255);
  float mean = stats[o], rstd = stats[256 + o];
  float sc = rstd * gamma[o];
  float sh = beta[o] - mean * sc;
  uint4 v = *(const uint4*)(outb + e);
  float4 r0, r1;
  r0.x = fmaxf(__uint_as_float(v.x << 16)          * sc + sh, 0.f);
  r0.y = fmaxf(__uint_as_float(v.x & 0xFFFF0000u)  * sc + sh, 0.f);
  r0.z = fmaxf(__uint_as_float(v.y << 16)          * sc + sh, 0.f);
  r0.w = fmaxf(__uint_as_float(v.y & 0xFFFF0000u)  * sc + sh, 0.f);
  r1.x = fmaxf(__uint_as_float(v.z << 16)          * sc + sh, 0.f);
  r1.y = fmaxf(__uint_as_float(v.z & 0xFFFF0000u)  * sc + sh, 0.f);
  r1.z = fmaxf(__uint_as_float(v.w << 16)          * sc + sh, 0.f);
  r1.w = fmaxf(__uint_as_float(v.w & 0xFFFF0000u)  * sc + sh, 0.f);
  *(float4*)(out + e)     = r0;
  *(float4*)(out + e + 4) = r1;
}

extern "C" void kernel_launch(void* const* d_in, const int* in_sizes, int n_in,
                              void* d_out, int out_size, void* d_ws, size_t ws_size,
                              hipStream_t stream){
  const float* x     = (const float*)d_in[0];
  const float* w_off = (const float*)d_in[1];
  const float* b_off = (const float*)d_in[2];
  const float* w     = (const float*)d_in[3];
  const float* gamma = (const float*)d_in[4];
  const float* beta  = (const float*)d_in[5];
  float* out = (float*)d_out;

  char* p = (char*)d_ws;
  ushort* xtp  = (ushort*)p; p += (size_t)Bb * PHW * Cin * 2;     // 17.31 MB (bf16)
  ushort* w2   = (ushort*)p; p += (size_t)Oout * CKd * 2;         // 1.18 MB (bf16)
  ushort* w2of = (ushort*)p; p += (size_t)32 * CKd * 2;           // 0.15 MB (bf16)
  int4*   pidx = (int4*)p;   p += (size_t)Bb * 9 * HWs * 16;      // 4.72 MB
  float4* pwt  = (float4*)p; p += (size_t)Bb * 9 * HWs * 16;      // 4.72 MB
  float*  parts= (float*)p;  p += (size_t)2 * 1024 * 256 * 4;     // 2.10 MB
  float*  stats= (float*)p;  p += 4096;                           // 4 KB
  ushort* outb = (ushort*)p; p += (size_t)Bb * Oout * HWs * 2;    // 16.78 MB (optional)
  size_t need = (size_t)(p - (char*)d_ws);

  k_prep_all<<<dim3(4898), dim3(256), 0, stream>>>(x, w, w_off, xtp, w2, w2of);
  k_offconv <<<dim3(512),  dim3(512), 0, stream>>>(xtp, w2of, b_off, pidx, pwt);
  if (ws_size >= need){
    k_main<1>  <<<dim3(256),  dim3(1024), 0, stream>>>(xtp, w2, pidx, pwt, (void*)outb, parts);
    k_bnstats  <<<dim3(256),  dim3(256), 0, stream>>>(parts, stats);
    k_bnapply_b<<<dim3(4096), dim3(256), 0, stream>>>(outb, out, stats, gamma, beta);
  } else {
    k_main<0>  <<<dim3(256),  dim3(1024), 0, stream>>>(xtp, w2, pidx, pwt, (void*)out, parts);
    k_bnstats  <<<dim3(256),  dim3(256), 0, stream>>>(parts, stats);
    k_bnapply  <<<dim3(8192), dim3(256), 0, stream>>>(out, stats, gamma, beta);
  }
}